// Round 1
// baseline (77080.402 us; speedup 1.0000x reference)
//
#include <hip/hip_runtime.h>

#define T_STEPS 512
#define BATCH 32
#define HID 1024
#define SEQ_BSTRIDE (T_STEPS * HID) // 524288: stride between batch rows of sequence

// ws layout (floats):
//   Ht[2 parity][2 layer][1024 h][32 b]  : 131072 floats
//   C [2 layer][1024 h][32 b]            : 65536 floats

__launch_bounds__(256, 1)
__global__ void lstm_step(const float* __restrict__ seq,
                          const float* __restrict__ Wh,
                          const float* __restrict__ Wx,
                          const float* __restrict__ Bias,
                          float* __restrict__ Ht,
                          float* __restrict__ C,
                          float* __restrict__ dout,
                          int t, int l, int write_out)
{
    // wlds[2 arr][16 row][260 pad] = 8320 floats; tail reused as gred(1024)+gl(512)
    __shared__ float wlds[8320];

    const int tid  = threadIdx.x;
    const int bq   = tid & 7;          // 8 quads of 4 batch
    const int hloc = (tid >> 3) & 3;   // 4 h per block
    const int g    = (tid >> 5) & 3;   // gate
    const int kH   = tid >> 7;         // K half: 0 = Wh*h, 1 = Wx*x
    const int hTile = blockIdx.x;
    const int h    = hTile * 4 + hloc;
    const int row  = g * 4 + hloc;     // 0..15

    const int pIn = t & 1, pOut = pIn ^ 1;
    const float* zh   = Ht + ((pIn * 2 + l) << 15);          // own-layer h_prev [1024][32]
    const float* zx_d = Ht + ((pOut * 2 + 0) << 15);         // layer-0 h_new (x for l==1)
    const float* xseq = seq + (size_t)t * HID;               // + b*SEQ_BSTRIDE + d (l==0)
    float* hOut = Ht + ((pOut * 2 + l) << 15);
    float* cPtr = C + (l << 15);

    // --- weight staging assignment: 32 (arr,row) pairs x 8 threads x 32 floats ---
    const int sp   = tid >> 3;          // 0..31
    const int sarr = sp >> 4;           // 0 = Wh, 1 = Wx
    const int srow = sp & 15;
    const int se   = (tid & 7) * 32;
    const int sg   = srow >> 2, shl = srow & 3;
    const float* wbase = (sarr ? Wx : Wh)
        + ((size_t)(l * 4 + sg) << 10) * 1024
        + (size_t)(hTile * 4 + shl) * 1024;
    float* wl_mine = &wlds[sarr * 4160 + srow * 260 + se];

    float acc0 = 0.f, acc1 = 0.f, acc2 = 0.f, acc3 = 0.f;

    // round-0 stage
    float4 pf[8];
    {
        const float4* gp = (const float4*)(wbase + se);
        #pragma unroll
        for (int q = 0; q < 8; ++q) pf[q] = gp[q];
        #pragma unroll
        for (int q = 0; q < 8; ++q) ((float4*)wl_mine)[q] = pf[q];
    }
    __syncthreads();

    const float* wl_read = &wlds[kH * 4160 + row * 260];

    for (int kc = 0; kc < 4; ++kc) {
        // prefetch next chunk into registers (overlaps with compute below)
        if (kc < 3) {
            const float4* gp = (const float4*)(wbase + (kc + 1) * 256 + se);
            #pragma unroll
            for (int q = 0; q < 8; ++q) pf[q] = gp[q];
        }

        if (kH == 0 || l == 1) {
            // d-major z: [d][32] layout, read z[d][bq*4..+3]
            const float* zd   = (kH == 0) ? zh : zx_d;
            const float* zrow = zd + ((kc << 8) << 5) + (bq << 2);
            #pragma unroll 4
            for (int d4 = 0; d4 < 64; ++d4) {
                float4 w4 = *(const float4*)(wl_read + (d4 << 2));
                float4 z0 = *(const float4*)(zrow + (((d4 << 2) + 0) << 5));
                float4 z1 = *(const float4*)(zrow + (((d4 << 2) + 1) << 5));
                float4 z2 = *(const float4*)(zrow + (((d4 << 2) + 2) << 5));
                float4 z3 = *(const float4*)(zrow + (((d4 << 2) + 3) << 5));
                acc0 = fmaf(w4.x, z0.x, acc0); acc1 = fmaf(w4.x, z0.y, acc1);
                acc2 = fmaf(w4.x, z0.z, acc2); acc3 = fmaf(w4.x, z0.w, acc3);
                acc0 = fmaf(w4.y, z1.x, acc0); acc1 = fmaf(w4.y, z1.y, acc1);
                acc2 = fmaf(w4.y, z1.z, acc2); acc3 = fmaf(w4.y, z1.w, acc3);
                acc0 = fmaf(w4.z, z2.x, acc0); acc1 = fmaf(w4.z, z2.y, acc1);
                acc2 = fmaf(w4.z, z2.z, acc2); acc3 = fmaf(w4.z, z2.w, acc3);
                acc0 = fmaf(w4.w, z3.x, acc0); acc1 = fmaf(w4.w, z3.y, acc1);
                acc2 = fmaf(w4.w, z3.z, acc2); acc3 = fmaf(w4.w, z3.w, acc3);
            }
        } else {
            // l==0, kH==1: x from sequence, b-major rows seq[b][t][d]
            const float* zb  = xseq + (kc << 8);
            const float* zr0 = zb + (size_t)(bq * 4 + 0) * SEQ_BSTRIDE;
            const float* zr1 = zb + (size_t)(bq * 4 + 1) * SEQ_BSTRIDE;
            const float* zr2 = zb + (size_t)(bq * 4 + 2) * SEQ_BSTRIDE;
            const float* zr3 = zb + (size_t)(bq * 4 + 3) * SEQ_BSTRIDE;
            #pragma unroll 4
            for (int d4 = 0; d4 < 64; ++d4) {
                float4 w4 = *(const float4*)(wl_read + (d4 << 2));
                float4 za = *(const float4*)(zr0 + (d4 << 2));
                float4 zbv = *(const float4*)(zr1 + (d4 << 2));
                float4 zc = *(const float4*)(zr2 + (d4 << 2));
                float4 zdv = *(const float4*)(zr3 + (d4 << 2));
                acc0 = fmaf(w4.x, za.x, acc0);  acc0 = fmaf(w4.y, za.y, acc0);
                acc0 = fmaf(w4.z, za.z, acc0);  acc0 = fmaf(w4.w, za.w, acc0);
                acc1 = fmaf(w4.x, zbv.x, acc1); acc1 = fmaf(w4.y, zbv.y, acc1);
                acc1 = fmaf(w4.z, zbv.z, acc1); acc1 = fmaf(w4.w, zbv.w, acc1);
                acc2 = fmaf(w4.x, zc.x, acc2);  acc2 = fmaf(w4.y, zc.y, acc2);
                acc2 = fmaf(w4.z, zc.z, acc2);  acc2 = fmaf(w4.w, zc.w, acc2);
                acc3 = fmaf(w4.x, zdv.x, acc3); acc3 = fmaf(w4.y, zdv.y, acc3);
                acc3 = fmaf(w4.z, zdv.z, acc3); acc3 = fmaf(w4.w, zdv.w, acc3);
            }
        }

        __syncthreads();           // everyone done reading wlds
        if (kc < 3) {
            #pragma unroll
            for (int q = 0; q < 8; ++q) ((float4*)wl_mine)[q] = pf[q];
        }
        __syncthreads();
    }

    // --- reduce K halves, add bias, activations ---
    float* gred = wlds;            // 1024 floats
    float* gl   = wlds + 1024;     // 512 floats
    *(float4*)&gred[tid << 2] = make_float4(acc0, acc1, acc2, acc3);
    __syncthreads();
    if (kH == 0) {
        const float4 other = *(const float4*)&gred[(tid + 128) << 2];
        const float bia = Bias[((l * 4 + g) << 10) + h];
        float* gdst = &gl[(g << 7) + (hloc << 5) + (bq << 2)];
        gdst[0] = acc0 + other.x + bia;
        gdst[1] = acc1 + other.y + bia;
        gdst[2] = acc2 + other.z + bia;
        gdst[3] = acc3 + other.w + bia;
    }
    __syncthreads();
    if (tid < 128) {
        const int hl = tid >> 5, b = tid & 31;
        const int hh = hTile * 4 + hl;
        const float gf = gl[(0 << 7) + (hl << 5) + b];
        const float gw = gl[(1 << 7) + (hl << 5) + b];
        const float gi = gl[(2 << 7) + (hl << 5) + b];
        const float go = gl[(3 << 7) + (hl << 5) + b];
        const int sidx = (hh << 5) + b;
        const float c_old = cPtr[sidx];
        const float sf = 1.f / (1.f + __expf(-gf));
        const float sw = 1.f / (1.f + __expf(-gw));
        const float ti = tanhf(gi);
        const float so = 1.f / (1.f + __expf(-go));
        const float c_new = c_old * sf + sw * ti;
        const float h_new = tanhf(c_new) * so;
        cPtr[sidx] = c_new;
        hOut[sidx] = h_new;
        if (write_out) dout[b * HID + hh] = h_new;
    }
}

extern "C" void kernel_launch(void* const* d_in, const int* in_sizes, int n_in,
                              void* d_out, int out_size, void* d_ws, size_t ws_size,
                              hipStream_t stream) {
    const float* seq  = (const float*)d_in[0];
    const float* Wh   = (const float*)d_in[1];
    const float* Wx   = (const float*)d_in[2];
    const float* Bias = (const float*)d_in[3];

    float* Ht = (float*)d_ws;            // 131072 floats
    float* C  = Ht + 131072;             // 65536 floats
    hipMemsetAsync(d_ws, 0, (size_t)(131072 + 65536) * sizeof(float), stream);

    for (int t = 0; t < T_STEPS; ++t) {
        for (int l = 0; l < 2; ++l) {
            const int wo = (t == T_STEPS - 1 && l == 1) ? 1 : 0;
            lstm_step<<<dim3(256), dim3(256), 0, stream>>>(
                seq, Wh, Wx, Bias, Ht, C, (float*)d_out, t, l, wo);
        }
    }
}

// Round 2
// 28949.631 us; speedup vs baseline: 2.6626x; 2.6626x over previous
//
#include <hip/hip_runtime.h>

#define T_STEPS 512
#define HID 1024
#define SEQ_BSTRIDE (T_STEPS * HID)

// LDS layout (dwords):
//   wl: [256 k][20] (16 rows + 4 pad)  base 0     size 5120
//   zl: [256 k][36] (32 b  + 4 pad)    base 5120  size 9216
//   total 14336 dw = 57344 B  (< 64 KB static limit)
// After compute, wl region reused: part[512 outputs][8 +swz] (<=4120 dw),
// gates gl[512] @ 4608.
#define WL 0
#define WSTR 20
#define ZL 5120
#define ZSTR 36
#define GLB 4608
#define LDS_DW 14336

__launch_bounds__(256, 1)
__global__ void lstm_step(const float* __restrict__ seq,
                          const float* __restrict__ Wh,
                          const float* __restrict__ Wx,
                          const float* __restrict__ Bias,
                          float* __restrict__ Ht,
                          float* __restrict__ C,
                          float* __restrict__ dout,
                          int t, int l, int write_out)
{
    __shared__ float lds[LDS_DW];
    const int tid = threadIdx.x;
    const int bid = blockIdx.x;

    // compute decomposition: tid = kg*8 + rowg*4 + bg
    const int kg   = tid >> 3;        // 0..31  K-group (k = kg + 32*i within chunk)
    const int rowg = (tid >> 2) & 1;  // 0..1   row half (8 rows each)
    const int bg   = tid & 3;         // 0..3   batch group (8 b each)

    const int pIn = t & 1, pOut = pIn ^ 1;
    const float* zh   = Ht + ((pIn * 2 + l) << 15);   // h_prev[l], [d][32]
    const float* zx_d = Ht + ((pOut * 2) << 15);      // layer-0 h_new (x for l==1)
    float* hOut = Ht + ((pOut * 2 + l) << 15);
    float* cPtr = C + (l << 15);

    // staging ids
    const int srow = tid >> 4;   // w stage: lds row/col 0..15  (g = srow>>2, hl = srow&3)
    const int skv  = tid & 15;   // w stage: k quad
    const int sdv  = tid >> 3;   // z dmaj: d lane 0..31
    const int sb4  = tid & 7;    // z dmaj: batch quad 0..7
    const int sb   = tid >> 3;   // z bmaj: batch 0..31
    const int sd8  = tid & 7;    // z bmaj: d quad 0..7

    const float* whbase = Wh + ((size_t)(((l * 4 + (srow >> 2)) << 10) + (bid << 2) + (srow & 3))) * 1024;
    const float* wxbase = Wx + ((size_t)(((l * 4 + (srow >> 2)) << 10) + (bid << 2) + (srow & 3))) * 1024;

    float4 pfw[4];
    float4 pfz[8];

    auto LOADC = [&](int c) {
        const float* wb = (c < 4) ? (whbase + c * 256) : (wxbase + (c - 4) * 256);
        #pragma unroll
        for (int j = 0; j < 4; ++j)
            pfw[j] = *(const float4*)(wb + j * 64 + skv * 4);
        if (c < 4) {
            const float* zsrc = zh + (c << 8) * 32;
            #pragma unroll
            for (int j = 0; j < 8; ++j)
                pfz[j] = *(const float4*)(zsrc + (j * 32 + sdv) * 32 + sb4 * 4);
        } else if (l == 1) {
            const float* zsrc = zx_d + ((c - 4) << 8) * 32;
            #pragma unroll
            for (int j = 0; j < 8; ++j)
                pfz[j] = *(const float4*)(zsrc + (j * 32 + sdv) * 32 + sb4 * 4);
        } else {
            const float* xs = seq + (size_t)sb * SEQ_BSTRIDE + t * HID + (c - 4) * 256;
            #pragma unroll
            for (int j = 0; j < 8; ++j)
                pfz[j] = *(const float4*)(xs + j * 32 + sd8 * 4);
        }
    };

    auto WRITEC = [&](int c) {
        #pragma unroll
        for (int j = 0; j < 4; ++j) {
            const int kk = j * 64 + skv * 4;
            lds[WL + (kk + 0) * WSTR + srow] = pfw[j].x;
            lds[WL + (kk + 1) * WSTR + srow] = pfw[j].y;
            lds[WL + (kk + 2) * WSTR + srow] = pfw[j].z;
            lds[WL + (kk + 3) * WSTR + srow] = pfw[j].w;
        }
        if (c < 4 || l == 1) {
            #pragma unroll
            for (int j = 0; j < 8; ++j)
                *(float4*)&lds[ZL + (j * 32 + sdv) * ZSTR + sb4 * 4] = pfz[j];
        } else {
            #pragma unroll
            for (int j = 0; j < 8; ++j) {
                const int dd = j * 32 + sd8 * 4;
                lds[ZL + (dd + 0) * ZSTR + sb] = pfz[j].x;
                lds[ZL + (dd + 1) * ZSTR + sb] = pfz[j].y;
                lds[ZL + (dd + 2) * ZSTR + sb] = pfz[j].z;
                lds[ZL + (dd + 3) * ZSTR + sb] = pfz[j].w;
            }
        }
    };

    float4 acc[8][2];
    #pragma unroll
    for (int r = 0; r < 8; ++r) {
        acc[r][0] = make_float4(0.f, 0.f, 0.f, 0.f);
        acc[r][1] = make_float4(0.f, 0.f, 0.f, 0.f);
    }

    LOADC(0);
    WRITEC(0);
    __syncthreads();

    const int wbase = WL + kg * WSTR + rowg * 8;
    const int zbase = ZL + kg * ZSTR + bg * 8;

    for (int c = 0; c < 8; ++c) {
        if (c < 7) LOADC(c + 1);   // global loads in flight during FMA

        #pragma unroll
        for (int i = 0; i < 8; ++i) {
            const float* wp = &lds[wbase + i * (32 * WSTR)];
            const float* zp = &lds[zbase + i * (32 * ZSTR)];
            const float4 wa  = *(const float4*)(wp);
            const float4 wb2 = *(const float4*)(wp + 4);
            const float4 za  = *(const float4*)(zp);
            const float4 zb2 = *(const float4*)(zp + 4);
            const float wr[8] = {wa.x, wa.y, wa.z, wa.w, wb2.x, wb2.y, wb2.z, wb2.w};
            #pragma unroll
            for (int r = 0; r < 8; ++r) {
                acc[r][0].x = fmaf(wr[r], za.x,  acc[r][0].x);
                acc[r][0].y = fmaf(wr[r], za.y,  acc[r][0].y);
                acc[r][0].z = fmaf(wr[r], za.z,  acc[r][0].z);
                acc[r][0].w = fmaf(wr[r], za.w,  acc[r][0].w);
                acc[r][1].x = fmaf(wr[r], zb2.x, acc[r][1].x);
                acc[r][1].y = fmaf(wr[r], zb2.y, acc[r][1].y);
                acc[r][1].z = fmaf(wr[r], zb2.z, acc[r][1].z);
                acc[r][1].w = fmaf(wr[r], zb2.w, acc[r][1].w);
            }
        }

        __syncthreads();                 // all LDS reads of this chunk done
        if (c < 7) {
            WRITEC(c + 1);
            __syncthreads();
        }
    }

    // ---- reduce over kg: 8 kg per wave via shfl_xor (lane bits 3..5) ----
    #pragma unroll
    for (int r = 0; r < 8; ++r) {
        #pragma unroll
        for (int q = 0; q < 2; ++q) {
            float4 v = acc[r][q];
            v.x += __shfl_xor(v.x, 8);  v.y += __shfl_xor(v.y, 8);
            v.z += __shfl_xor(v.z, 8);  v.w += __shfl_xor(v.w, 8);
            v.x += __shfl_xor(v.x, 16); v.y += __shfl_xor(v.y, 16);
            v.z += __shfl_xor(v.z, 16); v.w += __shfl_xor(v.w, 16);
            v.x += __shfl_xor(v.x, 32); v.y += __shfl_xor(v.y, 32);
            v.z += __shfl_xor(v.z, 32); v.w += __shfl_xor(v.w, 32);
            acc[r][q] = v;
        }
    }

    // ---- cross-wave partials: part[o][wv], swizzled, in wl region ----
    const int wv = tid >> 6;
    if ((tid & 56) == 0) {               // one lane per (rowg,bg) per wave
        #pragma unroll
        for (int r = 0; r < 8; ++r) {
            const float vals[8] = {acc[r][0].x, acc[r][0].y, acc[r][0].z, acc[r][0].w,
                                   acc[r][1].x, acc[r][1].y, acc[r][1].z, acc[r][1].w};
            #pragma unroll
            for (int b2 = 0; b2 < 8; ++b2) {
                const int o  = ((rowg * 8 + r) << 5) + bg * 8 + b2;
                const int sw = ((o >> 3) & 3) * 4 + ((o >> 8) & 1) * 16;
                lds[o * 8 + sw + wv] = vals[b2];
            }
        }
    }
    __syncthreads();

    // ---- sum 4 wave-partials, add bias ----
    #pragma unroll
    for (int ii = 0; ii < 2; ++ii) {
        const int o  = tid + ii * 256;
        const int sw = ((o >> 3) & 3) * 4 + ((o >> 8) & 1) * 16;
        const float4 p = *(const float4*)&lds[o * 8 + sw];
        float s = p.x + p.y + p.z + p.w;
        const int row = o >> 5;          // g*4 + hl
        const int g = row >> 2, hl = row & 3;
        s += Bias[((l * 4 + g) << 10) + (bid << 2) + hl];
        lds[GLB + o] = s;
    }
    __syncthreads();

    // ---- activations + state update ----
    if (tid < 128) {
        const int hl = tid >> 5, b = tid & 31;
        const float gf = lds[GLB + (0 * 4 + hl) * 32 + b];
        const float gw = lds[GLB + (1 * 4 + hl) * 32 + b];
        const float gi = lds[GLB + (2 * 4 + hl) * 32 + b];
        const float go = lds[GLB + (3 * 4 + hl) * 32 + b];
        const int h = (bid << 2) + hl;
        const int sidx = (h << 5) + b;
        const float c_old = cPtr[sidx];
        const float sf = 1.f / (1.f + __expf(-gf));
        const float sw2 = 1.f / (1.f + __expf(-gw));
        const float ti = tanhf(gi);
        const float so = 1.f / (1.f + __expf(-go));
        const float c_new = c_old * sf + sw2 * ti;
        const float h_new = tanhf(c_new) * so;
        cPtr[sidx] = c_new;
        hOut[sidx] = h_new;
        if (write_out) dout[b * HID + h] = h_new;
    }
}

extern "C" void kernel_launch(void* const* d_in, const int* in_sizes, int n_in,
                              void* d_out, int out_size, void* d_ws, size_t ws_size,
                              hipStream_t stream) {
    const float* seq  = (const float*)d_in[0];
    const float* Wh   = (const float*)d_in[1];
    const float* Wx   = (const float*)d_in[2];
    const float* Bias = (const float*)d_in[3];

    float* Ht = (float*)d_ws;            // [2 parity][2 layer][1024][32]
    float* C  = Ht + 131072;             // [2 layer][1024][32]
    hipMemsetAsync(d_ws, 0, (size_t)(131072 + 65536) * sizeof(float), stream);

    for (int t = 0; t < T_STEPS; ++t) {
        for (int l = 0; l < 2; ++l) {
            const int wo = (t == T_STEPS - 1 && l == 1) ? 1 : 0;
            lstm_step<<<dim3(256), dim3(256), 0, stream>>>(
                seq, Wh, Wx, Bias, Ht, C, (float*)d_out, t, l, wo);
        }
    }
}